// Round 14
// baseline (294.151 us; speedup 1.0000x reference)
//
#include <hip/hip_runtime.h>

typedef __bf16 bf16x8 __attribute__((ext_vector_type(8)));
typedef float f32x4 __attribute__((ext_vector_type(4)));
typedef _Float16 h4 __attribute__((ext_vector_type(4)));
typedef unsigned short u16;

#define ASYNC16(gp, lp) __builtin_amdgcn_global_load_lds( \
    (__attribute__((address_space(1))) void*)(gp),        \
    (__attribute__((address_space(3))) void*)(lp), 16, 0, 0)

// ---------------- helpers ----------------
static __device__ __forceinline__ u16 f2bf(float f) {
    union { float f; unsigned u; } v; v.f = f;
    unsigned r = v.u + 0x7FFFu + ((v.u >> 16) & 1u);   // RNE
    return (u16)(r >> 16);
}
static __device__ __forceinline__ u16 f2h(float f) {
    _Float16 h = (_Float16)f;
    union { _Float16 h; u16 u; } c; c.h = h;
    return c.u;
}
static __device__ __forceinline__ float bf2f(u16 b) {
    union { unsigned u; float f; } c; c.u = ((unsigned)b) << 16;
    return c.f;
}

#define QSCALE 0.18033688011112042f  /* 0.125 * log2(e) */

// ---------------- fused weight transpose+convert + x convert (1 launch) -------
__global__ void prep_weights(const float* __restrict__ W0, u16* __restrict__ O0,
                             const float* __restrict__ W1, u16* __restrict__ O1,
                             const float* __restrict__ W2, u16* __restrict__ O2,
                             const float* __restrict__ W3, u16* __restrict__ O3,
                             const float* __restrict__ X,  u16* __restrict__ XO) {
    int id = blockIdx.x;
    int t = threadIdx.y * 32 + threadIdx.x;
    if (id >= 8192) {
        size_t base = (size_t)(id - 8192) * 4096 + (size_t)t * 4;
        for (int i = 0; i < 4; i++) {
            float4 v = *(const float4*)&X[base + i * 1024];
            ushort4 o;
            o.x = f2bf(v.x); o.y = f2bf(v.y); o.z = f2bf(v.z); o.w = f2bf(v.w);
            *(ushort4*)&XO[base + i * 1024] = o;
        }
        return;
    }
    __shared__ float tile[32][33];
    const float* in; u16* out; int K, N, bx, by;
    if (id < 3072)      { in = W0; out = O0; K = 1024; N = 3072; bx = id % 96; by = id / 96; }
    else if (id < 4096) { id -= 3072; in = W1; out = O1; K = 1024; N = 1024; bx = id % 32; by = id / 32; }
    else if (id < 6144) { id -= 4096; in = W2; out = O2; K = 1024; N = 2048; bx = id % 64; by = id / 64; }
    else                { id -= 6144; in = W3; out = O3; K = 2048; N = 1024; bx = id % 32; by = id / 32; }
    int n0 = bx * 32, k0 = by * 32;
    int tx = threadIdx.x, ty = threadIdx.y;
    for (int i = 0; i < 4; i++)
        tile[ty + 8 * i][tx] = in[(size_t)(k0 + ty + 8 * i) * N + n0 + tx];
    __syncthreads();
    for (int i = 0; i < 4; i++)
        out[(size_t)(n0 + ty + 8 * i) * K + k0 + tx] = f2bf(tile[tx][ty + 8 * i]);
}

// V [bh][t][d] -> VT [bh][d][t]   grid(32, 32) block(64,8)  (u16 passthrough)
__global__ void vtrans_kernel(const u16* __restrict__ Vp, u16* __restrict__ VT) {
    __shared__ u16 tile[64 * 66];
    const int bh = blockIdx.y, t0 = blockIdx.x * 64;
    const int tx = threadIdx.x, ty = threadIdx.y;
    const u16* src = Vp + (size_t)bh * 2048 * 64;
    u16* dst = VT + (size_t)bh * 64 * 2048;
    for (int i = 0; i < 8; i++)
        tile[(ty + 8 * i) * 66 + tx] = src[(size_t)(t0 + ty + 8 * i) * 64 + tx];
    __syncthreads();
    for (int i = 0; i < 8; i++) {
        int d = ty + 8 * i;
        dst[(size_t)d * 2048 + t0 + tx] = tile[tx * 66 + d];
    }
}

// ---------------- GEMM 64x128, single-barrier pipeline (QKV / FF1) -------
// EPI 0: scatter to Q/K (bf16) + V (f16) [B,H,T,D]; Q scaled by QSCALE
// EPI 2: bf16 out = relu(acc + bias)
template <int EPI>
__global__ __launch_bounds__(256) void gemm64_kernel(
    const u16* __restrict__ A, const u16* __restrict__ BT,
    const float* __restrict__ bias, void* __restrict__ out0,
    int M, int N, int K,
    u16* __restrict__ q_out, u16* __restrict__ k_out, u16* __restrict__ v_out)
{
    __shared__ __align__(16) u16 As[2][64 * 32];
    __shared__ __align__(16) u16 Bs[2][128 * 32];
    const int tid = threadIdx.x;
    const int wave = tid >> 6, lane = tid & 63;
    const int quad = lane >> 4, l16 = lane & 15;
    const int m0 = blockIdx.y * 64, n0 = blockIdx.x * 128;
    const int wn = wave * 32;
    const int sr = tid >> 2, sc = (tid & 3) * 8;

    f32x4 acc[4][2] = {};

#define GISSUE(k0v, bb) do {                                                         \
        ASYNC16(&A[(size_t)(m0 + sr) * K + (k0v) + sc],       &As[bb][sr * 32 + sc]);        \
        ASYNC16(&BT[(size_t)(n0 + sr) * K + (k0v) + sc],      &Bs[bb][sr * 32 + sc]);        \
        ASYNC16(&BT[(size_t)(n0 + sr + 64) * K + (k0v) + sc], &Bs[bb][(sr + 64) * 32 + sc]); \
    } while (0)

    const int nk = K >> 5;
    GISSUE(0, 0);
    for (int it = 0; it < nk; it++) {
        __syncthreads();
        if (it + 1 < nk) GISSUE((it + 1) * 32, (it + 1) & 1);
        const u16* Ab = As[it & 1];
        const u16* Bb = Bs[it & 1];
        bf16x8 af[4], bfr[2];
        for (int i = 0; i < 4; i++)
            af[i] = *(const bf16x8*)&Ab[(i * 16 + l16) * 32 + quad * 8];
        for (int j = 0; j < 2; j++)
            bfr[j] = *(const bf16x8*)&Bb[(wn + j * 16 + l16) * 32 + quad * 8];
        for (int i = 0; i < 4; i++)
            for (int j = 0; j < 2; j++)
                acc[i][j] = __builtin_amdgcn_mfma_f32_16x16x32_bf16(af[i], bfr[j], acc[i][j], 0, 0, 0);
    }
#undef GISSUE

    for (int i = 0; i < 4; i++) {
        int mbase = m0 + i * 16 + quad * 4;
        for (int j = 0; j < 2; j++) {
            int n = n0 + wn + j * 16 + l16;
            float bv = bias[n];
            for (int r = 0; r < 4; r++) {
                int m = mbase + r;
                float v = acc[i][j][r] + bv;
                if (EPI == 0) {
                    int s = n >> 10, rr = n & 1023, h = rr >> 6, d = rr & 63;
                    int b = m >> 11, t = m & 2047;
                    if (s == 0) v *= QSCALE;
                    u16* dst = (s == 0) ? q_out : (s == 1) ? k_out : v_out;
                    u16 bits = (s == 2) ? f2h(v) : f2bf(v);
                    dst[((size_t)((b * 16 + h) * 2048 + t)) * 64 + d] = bits;
                } else {
                    ((u16*)out0)[(size_t)m * N + n] = f2bf(fmaxf(v, 0.f));
                }
            }
        }
    }
}

// ---------------- GEMM 64x64 BK=64 two-panel (out-proj / FF2) -------
// RESBF=0: fp32 resid; RESBF=1: bf16 resid.
template <int RESBF>
__global__ __launch_bounds__(256) void gemm64x64_kernel(
    const u16* __restrict__ A, const u16* __restrict__ BT,
    const float* __restrict__ bias, float* __restrict__ out0,
    const void* __restrict__ resid, int M, int N, int K)
{
    __shared__ __align__(16) u16 As[2][2][64][32];
    __shared__ __align__(16) u16 Bs[2][2][64][32];
    const int tid = threadIdx.x;
    const int wave = tid >> 6, lane = tid & 63;
    const int quad = lane >> 4, l16 = lane & 15;
    const int m0 = blockIdx.y * 64, n0 = blockIdx.x * 64;
    const int wm = (wave >> 1) * 32, wn = (wave & 1) * 32;
    const int sr = tid >> 2, sc = (tid & 3) * 8;

    f32x4 acc[2][2] = {};

#define GISSUE(k0v, bb) do {                                                          \
        ASYNC16(&A[(size_t)(m0 + sr) * K + (k0v) + sc],       &As[bb][0][sr][sc]);    \
        ASYNC16(&A[(size_t)(m0 + sr) * K + (k0v) + 32 + sc],  &As[bb][1][sr][sc]);    \
        ASYNC16(&BT[(size_t)(n0 + sr) * K + (k0v) + sc],      &Bs[bb][0][sr][sc]);    \
        ASYNC16(&BT[(size_t)(n0 + sr) * K + (k0v) + 32 + sc], &Bs[bb][1][sr][sc]);    \
    } while (0)

    const int nk = K >> 6;
    GISSUE(0, 0);
    for (int it = 0; it < nk; it++) {
        __syncthreads();
        if (it + 1 < nk) GISSUE((it + 1) * 64, (it + 1) & 1);
        const int cur = it & 1;
        for (int h = 0; h < 2; h++) {
            bf16x8 af[2], bfr[2];
            for (int i = 0; i < 2; i++)
                af[i] = *(const bf16x8*)&As[cur][h][wm + i * 16 + l16][quad * 8];
            for (int j = 0; j < 2; j++)
                bfr[j] = *(const bf16x8*)&Bs[cur][h][wn + j * 16 + l16][quad * 8];
            for (int i = 0; i < 2; i++)
                for (int j = 0; j < 2; j++)
                    acc[i][j] = __builtin_amdgcn_mfma_f32_16x16x32_bf16(af[i], bfr[j], acc[i][j], 0, 0, 0);
        }
    }
#undef GISSUE

    for (int i = 0; i < 2; i++) {
        int mbase = m0 + wm + i * 16 + quad * 4;
        for (int j = 0; j < 2; j++) {
            int n = n0 + wn + j * 16 + l16;
            float bv = bias[n];
            for (int r = 0; r < 4; r++) {
                int m = mbase + r;
                float rv = RESBF ? bf2f(((const u16*)resid)[(size_t)m * N + n])
                                 : ((const float*)resid)[(size_t)m * N + n];
                out0[(size_t)m * N + n] = acc[i][j][r] + bv + rv;
            }
        }
    }
}

// ---------------- flash attention v10: in-register P + padded V ----
__global__ __launch_bounds__(256) void attn_kernel(
    const u16* __restrict__ Qp, const u16* __restrict__ Kp,
    const u16* __restrict__ VTg, u16* __restrict__ Hb)
{
    __shared__ __align__(16) u16 Ks[2][2][64][32];   // [buf][d-panel][t][d] bf16
    __shared__ __align__(16) u16 Vs[2][2][64][36];   // [buf][t-panel][d][t+pad] f16
    const int tid = threadIdx.x;
    const int wave = tid >> 6, lane = tid & 63;
    const int quad = lane >> 4, l16 = lane & 15;
    const int bh = ((blockIdx.x & 7) << 2) | ((blockIdx.x >> 3) & 3);
    const int qt = 31 - (blockIdx.x >> 5);           // heavy tiles first
    const int nk = qt + 1;
    const size_t kbase = (size_t)bh * 2048 * 64;
    const u16* Vt = VTg + (size_t)bh * 64 * 2048;

    const int qrow = qt * 64 + wave * 16;
    const int qg = qrow + l16;                       // this lane's q (S^T col)
    bf16x8 qf[2];
    for (int c = 0; c < 2; c++)
        qf[c] = *(const bf16x8*)&Qp[kbase + (size_t)(qrow + l16) * 64 + c * 32 + quad * 8];

    f32x4 o[4] = {};
    float lsum = 0.f;

    const int srow = tid >> 2, sc8 = (tid & 3) * 8;  // K rows
    const int vd = tid >> 2, vq = tid & 3;           // V: d row, t-quarter
    const int vp = vq >> 1, vw = (vq & 1) * 16;

#define KISSUE(k0v, b) do {                                                                 \
        ASYNC16(&Kp[kbase + (size_t)((k0v) + srow) * 64 + sc8],      &Ks[b][0][srow][sc8]); \
        ASYNC16(&Kp[kbase + (size_t)((k0v) + srow) * 64 + 32 + sc8], &Ks[b][1][srow][sc8]); \
    } while (0)
#define VLOAD(k0v) do {                                                           \
        vr0 = *(const uint4*)&Vt[(size_t)vd * 2048 + (k0v) + vq * 16];            \
        vr1 = *(const uint4*)&Vt[(size_t)vd * 2048 + (k0v) + vq * 16 + 8];        \
    } while (0)
#define VSTORE(b) do {                                                            \
        *(uint2*)&Vs[b][vp][vd][vw]      = make_uint2(vr0.x, vr0.y);              \
        *(uint2*)&Vs[b][vp][vd][vw + 4]  = make_uint2(vr0.z, vr0.w);              \
        *(uint2*)&Vs[b][vp][vd][vw + 8]  = make_uint2(vr1.x, vr1.y);              \
        *(uint2*)&Vs[b][vp][vd][vw + 12] = make_uint2(vr1.z, vr1.w);              \
    } while (0)

    uint4 vr0, vr1;
    VLOAD(0); KISSUE(0, 0); VSTORE(0);
    for (int g = 0; g < nk; g++) {
        __syncthreads();
        const int cur = g & 1, nxt = cur ^ 1;
        const bool more = (g + 1 < nk);
        if (more) { VLOAD((g + 1) * 64); KISSUE((g + 1) * 64, nxt); }
        const int k0 = g * 64;
        const bool diag = (g == nk - 1);

        f32x4 st[4];
        for (int kt = 0; kt < 4; kt++) {
            f32x4 a = {0.f, 0.f, 0.f, 0.f};
            a = __builtin_amdgcn_mfma_f32_16x16x32_bf16(
                    *(const bf16x8*)&Ks[cur][0][kt * 16 + l16][quad * 8], qf[0], a, 0, 0, 0);
            a = __builtin_amdgcn_mfma_f32_16x16x32_bf16(
                    *(const bf16x8*)&Ks[cur][1][kt * 16 + l16][quad * 8], qf[1], a, 0, 0, 0);
            st[kt] = a;
        }
        for (int kt = 0; kt < 4; kt++) {
            h4 pa;
            if (diag) {
                for (int r = 0; r < 4; r++) {
                    int tg = k0 + kt * 16 + quad * 4 + r;
                    float p = (tg <= qg) ? __builtin_amdgcn_exp2f(st[kt][r]) : 0.f;
                    lsum += p; pa[r] = (_Float16)p;
                }
            } else {
                for (int r = 0; r < 4; r++) {
                    float p = __builtin_amdgcn_exp2f(st[kt][r]);
                    lsum += p; pa[r] = (_Float16)p;
                }
            }
            const int tp = kt >> 1, tw = (kt & 1) * 16 + quad * 4;
            for (int dc = 0; dc < 4; dc++) {
                h4 vb = *(const h4*)&Vs[cur][tp][dc * 16 + l16][tw];
                o[dc] = __builtin_amdgcn_mfma_f32_16x16x16f16(pa, vb, o[dc], 0, 0, 0);
            }
        }
        if (more) VSTORE(nxt);
    }
#undef KISSUE
#undef VLOAD
#undef VSTORE

    lsum += __shfl_xor(lsum, 16, 64);
    lsum += __shfl_xor(lsum, 32, 64);
    float rinv = 1.f / lsum;
    float rq[4];
    for (int r = 0; r < 4; r++)
        rq[r] = __shfl(rinv, quad * 4 + r, 64);

    const int b = bh >> 4, h = bh & 15;
    for (int dc = 0; dc < 4; dc++)
        for (int r = 0; r < 4; r++) {
            int q = qrow + quad * 4 + r;
            Hb[((size_t)(b * 2048 + q)) * 1024 + h * 64 + dc * 16 + l16] = f2bf(o[dc][r] * rq[r]);
        }
}

// ---------------- layernorm (row = block), optional bf16 copy ----------------
__global__ __launch_bounds__(256) void ln_kernel(
    float* __restrict__ y, const float* __restrict__ g, const float* __restrict__ be,
    u16* __restrict__ bf_out)
{
    __shared__ float red[8];
    const int row = blockIdx.x, tid = threadIdx.x;
    float4 v = *(const float4*)&y[(size_t)row * 1024 + tid * 4];
    float sum = v.x + v.y + v.z + v.w;
    float sq  = v.x * v.x + v.y * v.y + v.z * v.z + v.w * v.w;
    for (int off = 1; off < 64; off <<= 1) {
        sum += __shfl_xor(sum, off, 64);
        sq  += __shfl_xor(sq,  off, 64);
    }
    int wave = tid >> 6;
    if ((tid & 63) == 0) { red[wave * 2] = sum; red[wave * 2 + 1] = sq; }
    __syncthreads();
    sum = red[0] + red[2] + red[4] + red[6];
    sq  = red[1] + red[3] + red[5] + red[7];
    float mu = sum * (1.f / 1024.f);
    float var = sq * (1.f / 1024.f) - mu * mu;
    float rstd = rsqrtf(var + 1e-5f);
    float4 gv = *(const float4*)&g[tid * 4];
    float4 bv = *(const float4*)&be[tid * 4];
    float4 ov;
    ov.x = (v.x - mu) * rstd * gv.x + bv.x;
    ov.y = (v.y - mu) * rstd * gv.y + bv.y;
    ov.z = (v.z - mu) * rstd * gv.z + bv.z;
    ov.w = (v.w - mu) * rstd * gv.w + bv.w;
    *(float4*)&y[(size_t)row * 1024 + tid * 4] = ov;
    if (bf_out) {
        ushort4 ob;
        ob.x = f2bf(ov.x); ob.y = f2bf(ov.y); ob.z = f2bf(ov.z); ob.w = f2bf(ov.w);
        *(ushort4*)&bf_out[(size_t)row * 1024 + tid * 4] = ob;
    }
}

// ---------------- launch ----------------
extern "C" void kernel_launch(void* const* d_in, const int* in_sizes, int n_in,
                              void* d_out, int out_size, void* d_ws, size_t ws_size,
                              hipStream_t stream)
{
    const float* x     = (const float*)d_in[0];
    const float* Wqkv  = (const float*)d_in[1];
    const float* bqkv  = (const float*)d_in[2];
    const float* Wout  = (const float*)d_in[3];
    const float* bout  = (const float*)d_in[4];
    const float* g1    = (const float*)d_in[5];
    const float* be1   = (const float*)d_in[6];
    const float* Wff1  = (const float*)d_in[7];
    const float* bff1  = (const float*)d_in[8];
    const float* Wff2  = (const float*)d_in[9];
    const float* bff2  = (const float*)d_in[10];
    const float* g2    = (const float*)d_in[11];
    const float* be2   = (const float*)d_in[12];
    float* out = (float*)d_out;

    char* wsb = (char*)d_ws;
    u16* WqkvT = (u16*)(wsb + 0);                   //  6 MB [3072,1024]
    u16* WoutT = (u16*)(wsb + 6291456);             //  2 MB [1024,1024]
    u16* Wff1T = (u16*)(wsb + 8388608);             //  4 MB [2048,1024]
    u16* Wff2T = (u16*)(wsb + 12582912);            //  4 MB [1024,2048]
    u16* xb    = (u16*)(wsb + 16777216);            //  8 MB [4096,1024]; reused as VT
    u16* Qp    = (u16*)(wsb + 25165824);            //  8 MB [B,H,T,D] bf16
    u16* Kp    = (u16*)(wsb + 33554432);            //  8 MB bf16
    u16* Vp    = (u16*)(wsb + 41943040);            //  8 MB f16
    u16* Hb    = (u16*)(wsb + 50331648);            //  8 MB [4096,1024] bf16
    u16* x1b   = (u16*)(wsb + 58720256);            //  8 MB [4096,1024] bf16
    u16* ff1b  = (u16*)(wsb + 67108864);            // 16 MB [4096,2048] bf16
    float* y1  = (float*)(wsb + 83886080);          // 16 MB fp32 [4096,1024]
    u16* VTg   = xb;                                // V^T f16 [bh][d][t]

    // fused weight prep (4 transposes + x convert in 1 launch)
    hipLaunchKernelGGL(prep_weights, dim3(9216), dim3(32, 8), 0, stream,
                       Wqkv, WqkvT, Wout, WoutT, Wff1, Wff1T, Wff2, Wff2T, x, xb);

    // QKV projection (64x128 tiles, 1536 blocks => ~6 blocks/CU)
    hipLaunchKernelGGL((gemm64_kernel<0>), dim3(24, 64), dim3(256), 0, stream,
                       xb, WqkvT, bqkv, nullptr, 4096, 3072, 1024, Qp, Kp, Vp);
    // V transpose (f16 passthrough; overwrites xb — dead now)
    hipLaunchKernelGGL(vtrans_kernel, dim3(32, 32), dim3(64, 8), 0, stream, Vp, VTg);
    // attention (v10)
    hipLaunchKernelGGL(attn_kernel, dim3(1024), dim3(256), 0, stream, Qp, Kp, VTg, Hb);
    // out projection + residual (x fp32) -> y1 fp32   (64x64 BK=64, 1024 blocks)
    hipLaunchKernelGGL((gemm64x64_kernel<0>), dim3(16, 64), dim3(256), 0, stream,
                       Hb, WoutT, bout, y1, (const void*)x, 4096, 1024, 1024);
    // LN1 in-place on y1, emit bf16 x1b
    hipLaunchKernelGGL(ln_kernel, dim3(4096), dim3(256), 0, stream, y1, g1, be1, x1b);
    // FF1 + relu -> ff1b bf16   (64x128, 1024 blocks)
    hipLaunchKernelGGL((gemm64_kernel<2>), dim3(16, 64), dim3(256), 0, stream,
                       x1b, Wff1T, bff1, (void*)ff1b, 4096, 2048, 1024,
                       (u16*)nullptr, (u16*)nullptr, (u16*)nullptr);
    // FF2 + residual (x1b bf16) -> d_out fp32   (64x64 BK=64, 1024 blocks)
    hipLaunchKernelGGL((gemm64x64_kernel<1>), dim3(16, 64), dim3(256), 0, stream,
                       ff1b, Wff2T, bff2, out, (const void*)x1b, 4096, 1024, 2048);
    // LN2 in-place on d_out
    hipLaunchKernelGGL(ln_kernel, dim3(4096), dim3(256), 0, stream, out, g2, be2, (u16*)nullptr);
}

// Round 15
// 291.740 us; speedup vs baseline: 1.0083x; 1.0083x over previous
//
#include <hip/hip_runtime.h>

typedef __bf16 bf16x8 __attribute__((ext_vector_type(8)));
typedef float f32x4 __attribute__((ext_vector_type(4)));
typedef _Float16 h4 __attribute__((ext_vector_type(4)));
typedef unsigned short u16;

#define ASYNC16(gp, lp) __builtin_amdgcn_global_load_lds( \
    (__attribute__((address_space(1))) void*)(gp),        \
    (__attribute__((address_space(3))) void*)(lp), 16, 0, 0)

// ---------------- helpers ----------------
static __device__ __forceinline__ u16 f2bf(float f) {
    union { float f; unsigned u; } v; v.f = f;
    unsigned r = v.u + 0x7FFFu + ((v.u >> 16) & 1u);   // RNE
    return (u16)(r >> 16);
}
static __device__ __forceinline__ u16 f2h(float f) {
    _Float16 h = (_Float16)f;
    union { _Float16 h; u16 u; } c; c.h = h;
    return c.u;
}
static __device__ __forceinline__ float bf2f(u16 b) {
    union { unsigned u; float f; } c; c.u = ((unsigned)b) << 16;
    return c.f;
}

#define QSCALE 0.18033688011112042f  /* 0.125 * log2(e) */

// ---------------- fused weight transpose+convert + x convert (1 launch) -------
__global__ void prep_weights(const float* __restrict__ W0, u16* __restrict__ O0,
                             const float* __restrict__ W1, u16* __restrict__ O1,
                             const float* __restrict__ W2, u16* __restrict__ O2,
                             const float* __restrict__ W3, u16* __restrict__ O3,
                             const float* __restrict__ X,  u16* __restrict__ XO) {
    int id = blockIdx.x;
    int t = threadIdx.y * 32 + threadIdx.x;
    if (id >= 8192) {
        size_t base = (size_t)(id - 8192) * 4096 + (size_t)t * 4;
        for (int i = 0; i < 4; i++) {
            float4 v = *(const float4*)&X[base + i * 1024];
            ushort4 o;
            o.x = f2bf(v.x); o.y = f2bf(v.y); o.z = f2bf(v.z); o.w = f2bf(v.w);
            *(ushort4*)&XO[base + i * 1024] = o;
        }
        return;
    }
    __shared__ float tile[32][33];
    const float* in; u16* out; int K, N, bx, by;
    if (id < 3072)      { in = W0; out = O0; K = 1024; N = 3072; bx = id % 96; by = id / 96; }
    else if (id < 4096) { id -= 3072; in = W1; out = O1; K = 1024; N = 1024; bx = id % 32; by = id / 32; }
    else if (id < 6144) { id -= 4096; in = W2; out = O2; K = 1024; N = 2048; bx = id % 64; by = id / 64; }
    else                { id -= 6144; in = W3; out = O3; K = 2048; N = 1024; bx = id % 32; by = id / 32; }
    int n0 = bx * 32, k0 = by * 32;
    int tx = threadIdx.x, ty = threadIdx.y;
    for (int i = 0; i < 4; i++)
        tile[ty + 8 * i][tx] = in[(size_t)(k0 + ty + 8 * i) * N + n0 + tx];
    __syncthreads();
    for (int i = 0; i < 4; i++)
        out[(size_t)(n0 + ty + 8 * i) * K + k0 + tx] = f2bf(tile[tx][ty + 8 * i]);
}

// V [bh][t][d] -> VT [bh][d][t]   grid(32, 32) block(64,8)  (u16 passthrough)
__global__ void vtrans_kernel(const u16* __restrict__ Vp, u16* __restrict__ VT) {
    __shared__ u16 tile[64 * 66];
    const int bh = blockIdx.y, t0 = blockIdx.x * 64;
    const int tx = threadIdx.x, ty = threadIdx.y;
    const u16* src = Vp + (size_t)bh * 2048 * 64;
    u16* dst = VT + (size_t)bh * 64 * 2048;
    for (int i = 0; i < 8; i++)
        tile[(ty + 8 * i) * 66 + tx] = src[(size_t)(t0 + ty + 8 * i) * 64 + tx];
    __syncthreads();
    for (int i = 0; i < 8; i++) {
        int d = ty + 8 * i;
        dst[(size_t)d * 2048 + t0 + tx] = tile[tx * 66 + d];
    }
}

// ---------------- QKV GEMM 128x128, single-barrier pipeline, XCD swizzle -------
// Scatter epilogue: Q/K (bf16) + V (f16) [B,H,T,D]; Q scaled by QSCALE.
// Grid = 768 (1D). Swizzle: xcd = id%8 serves n_tiles {3x..3x+2} (B panel
// 0.75 MB stays L2-resident per XCD; A panels read 3x temporally adjacent).
__global__ __launch_bounds__(256) void gemm_qkv_kernel(
    const u16* __restrict__ A, const u16* __restrict__ BT,
    const float* __restrict__ bias,
    u16* __restrict__ q_out, u16* __restrict__ k_out, u16* __restrict__ v_out)
{
    const int K = 1024, N = 3072;
    __shared__ __align__(16) u16 As[2][128 * 32];
    __shared__ __align__(16) u16 Bs[2][128 * 32];
    const int tid = threadIdx.x;
    const int wave = tid >> 6, lane = tid & 63;
    const int quad = lane >> 4, l16 = lane & 15;
    const int id = blockIdx.x;
    const int n_t = (id & 7) * 3 + ((id >> 3) % 3);
    const int m_t = (id >> 3) / 3;
    const int m0 = m_t * 128, n0 = n_t * 128;
    const int wm = (wave >> 1) * 64, wn = (wave & 1) * 64;
    const int sr = tid >> 2, sc = (tid & 3) * 8;

    f32x4 acc[4][4] = {};

#define GISSUE(k0v, bb) do {                                                         \
        ASYNC16(&A[(size_t)(m0 + sr) * K + (k0v) + sc],       &As[bb][sr * 32 + sc]);        \
        ASYNC16(&A[(size_t)(m0 + sr + 64) * K + (k0v) + sc],  &As[bb][(sr + 64) * 32 + sc]); \
        ASYNC16(&BT[(size_t)(n0 + sr) * K + (k0v) + sc],      &Bs[bb][sr * 32 + sc]);        \
        ASYNC16(&BT[(size_t)(n0 + sr + 64) * K + (k0v) + sc], &Bs[bb][(sr + 64) * 32 + sc]); \
    } while (0)

    const int nk = K >> 5;
    GISSUE(0, 0);
    for (int it = 0; it < nk; it++) {
        __syncthreads();
        if (it + 1 < nk) GISSUE((it + 1) * 32, (it + 1) & 1);
        const u16* Ab = As[it & 1];
        const u16* Bb = Bs[it & 1];
        bf16x8 af[4], bfr[4];
        for (int i = 0; i < 4; i++) {
            af[i]  = *(const bf16x8*)&Ab[(wm + i * 16 + l16) * 32 + quad * 8];
            bfr[i] = *(const bf16x8*)&Bb[(wn + i * 16 + l16) * 32 + quad * 8];
        }
        for (int i = 0; i < 4; i++)
            for (int j = 0; j < 4; j++)
                acc[i][j] = __builtin_amdgcn_mfma_f32_16x16x32_bf16(af[i], bfr[j], acc[i][j], 0, 0, 0);
    }
#undef GISSUE

    for (int i = 0; i < 4; i++) {
        int mbase = m0 + wm + i * 16 + quad * 4;
        for (int j = 0; j < 4; j++) {
            int n = n0 + wn + j * 16 + l16;
            float bv = bias[n];
            for (int r = 0; r < 4; r++) {
                int m = mbase + r;
                float v = acc[i][j][r] + bv;
                int s = n >> 10, rr = n & 1023, h = rr >> 6, d = rr & 63;
                int b = m >> 11, t = m & 2047;
                if (s == 0) v *= QSCALE;
                u16* dst = (s == 0) ? q_out : (s == 1) ? k_out : v_out;
                u16 bits = (s == 2) ? f2h(v) : f2bf(v);
                dst[((size_t)((b * 16 + h) * 2048 + t)) * 64 + d] = bits;
            }
        }
    }
}

// ---------------- GEMM 64x128 (FF1: 1024 blocks => 4 blocks/CU) -------
// EPI 2: bf16 out = relu(acc + bias)
__global__ __launch_bounds__(256) void gemm64_kernel(
    const u16* __restrict__ A, const u16* __restrict__ BT,
    const float* __restrict__ bias, u16* __restrict__ out0,
    int M, int N, int K)
{
    __shared__ __align__(16) u16 As[2][64 * 32];
    __shared__ __align__(16) u16 Bs[2][128 * 32];
    const int tid = threadIdx.x;
    const int wave = tid >> 6, lane = tid & 63;
    const int quad = lane >> 4, l16 = lane & 15;
    const int m0 = blockIdx.y * 64, n0 = blockIdx.x * 128;
    const int wn = wave * 32;
    const int sr = tid >> 2, sc = (tid & 3) * 8;

    f32x4 acc[4][2] = {};

#define GISSUE(k0v, bb) do {                                                         \
        ASYNC16(&A[(size_t)(m0 + sr) * K + (k0v) + sc],       &As[bb][sr * 32 + sc]);        \
        ASYNC16(&BT[(size_t)(n0 + sr) * K + (k0v) + sc],      &Bs[bb][sr * 32 + sc]);        \
        ASYNC16(&BT[(size_t)(n0 + sr + 64) * K + (k0v) + sc], &Bs[bb][(sr + 64) * 32 + sc]); \
    } while (0)

    const int nk = K >> 5;
    GISSUE(0, 0);
    for (int it = 0; it < nk; it++) {
        __syncthreads();
        if (it + 1 < nk) GISSUE((it + 1) * 32, (it + 1) & 1);
        const u16* Ab = As[it & 1];
        const u16* Bb = Bs[it & 1];
        bf16x8 af[4], bfr[2];
        for (int i = 0; i < 4; i++)
            af[i] = *(const bf16x8*)&Ab[(i * 16 + l16) * 32 + quad * 8];
        for (int j = 0; j < 2; j++)
            bfr[j] = *(const bf16x8*)&Bb[(wn + j * 16 + l16) * 32 + quad * 8];
        for (int i = 0; i < 4; i++)
            for (int j = 0; j < 2; j++)
                acc[i][j] = __builtin_amdgcn_mfma_f32_16x16x32_bf16(af[i], bfr[j], acc[i][j], 0, 0, 0);
    }
#undef GISSUE

    for (int i = 0; i < 4; i++) {
        int mbase = m0 + i * 16 + quad * 4;
        for (int j = 0; j < 2; j++) {
            int n = n0 + wn + j * 16 + l16;
            float bv = bias[n];
            for (int r = 0; r < 4; r++) {
                int m = mbase + r;
                out0[(size_t)m * N + n] = f2bf(fmaxf(acc[i][j][r] + bv, 0.f));
            }
        }
    }
}

// ---------------- GEMM 64x64 BK=64 two-panel (out-proj / FF2) -------
// RESBF=0: fp32 resid; RESBF=1: bf16 resid.
template <int RESBF>
__global__ __launch_bounds__(256) void gemm64x64_kernel(
    const u16* __restrict__ A, const u16* __restrict__ BT,
    const float* __restrict__ bias, float* __restrict__ out0,
    const void* __restrict__ resid, int M, int N, int K)
{
    __shared__ __align__(16) u16 As[2][2][64][32];
    __shared__ __align__(16) u16 Bs[2][2][64][32];
    const int tid = threadIdx.x;
    const int wave = tid >> 6, lane = tid & 63;
    const int quad = lane >> 4, l16 = lane & 15;
    const int m0 = blockIdx.y * 64, n0 = blockIdx.x * 64;
    const int wm = (wave >> 1) * 32, wn = (wave & 1) * 32;
    const int sr = tid >> 2, sc = (tid & 3) * 8;

    f32x4 acc[2][2] = {};

#define GISSUE(k0v, bb) do {                                                          \
        ASYNC16(&A[(size_t)(m0 + sr) * K + (k0v) + sc],       &As[bb][0][sr][sc]);    \
        ASYNC16(&A[(size_t)(m0 + sr) * K + (k0v) + 32 + sc],  &As[bb][1][sr][sc]);    \
        ASYNC16(&BT[(size_t)(n0 + sr) * K + (k0v) + sc],      &Bs[bb][0][sr][sc]);    \
        ASYNC16(&BT[(size_t)(n0 + sr) * K + (k0v) + 32 + sc], &Bs[bb][1][sr][sc]);    \
    } while (0)

    const int nk = K >> 6;
    GISSUE(0, 0);
    for (int it = 0; it < nk; it++) {
        __syncthreads();
        if (it + 1 < nk) GISSUE((it + 1) * 64, (it + 1) & 1);
        const int cur = it & 1;
        for (int h = 0; h < 2; h++) {
            bf16x8 af[2], bfr[2];
            for (int i = 0; i < 2; i++)
                af[i] = *(const bf16x8*)&As[cur][h][wm + i * 16 + l16][quad * 8];
            for (int j = 0; j < 2; j++)
                bfr[j] = *(const bf16x8*)&Bs[cur][h][wn + j * 16 + l16][quad * 8];
            for (int i = 0; i < 2; i++)
                for (int j = 0; j < 2; j++)
                    acc[i][j] = __builtin_amdgcn_mfma_f32_16x16x32_bf16(af[i], bfr[j], acc[i][j], 0, 0, 0);
        }
    }
#undef GISSUE

    for (int i = 0; i < 2; i++) {
        int mbase = m0 + wm + i * 16 + quad * 4;
        for (int j = 0; j < 2; j++) {
            int n = n0 + wn + j * 16 + l16;
            float bv = bias[n];
            for (int r = 0; r < 4; r++) {
                int m = mbase + r;
                float rv = RESBF ? bf2f(((const u16*)resid)[(size_t)m * N + n])
                                 : ((const float*)resid)[(size_t)m * N + n];
                out0[(size_t)m * N + n] = acc[i][j][r] + bv + rv;
            }
        }
    }
}

// ---------------- flash attention v10: in-register P + padded V ----
__global__ __launch_bounds__(256) void attn_kernel(
    const u16* __restrict__ Qp, const u16* __restrict__ Kp,
    const u16* __restrict__ VTg, u16* __restrict__ Hb)
{
    __shared__ __align__(16) u16 Ks[2][2][64][32];   // [buf][d-panel][t][d] bf16
    __shared__ __align__(16) u16 Vs[2][2][64][36];   // [buf][t-panel][d][t+pad] f16
    const int tid = threadIdx.x;
    const int wave = tid >> 6, lane = tid & 63;
    const int quad = lane >> 4, l16 = lane & 15;
    const int bh = ((blockIdx.x & 7) << 2) | ((blockIdx.x >> 3) & 3);
    const int qt = 31 - (blockIdx.x >> 5);           // heavy tiles first
    const int nk = qt + 1;
    const size_t kbase = (size_t)bh * 2048 * 64;
    const u16* Vt = VTg + (size_t)bh * 64 * 2048;

    const int qrow = qt * 64 + wave * 16;
    const int qg = qrow + l16;                       // this lane's q (S^T col)
    bf16x8 qf[2];
    for (int c = 0; c < 2; c++)
        qf[c] = *(const bf16x8*)&Qp[kbase + (size_t)(qrow + l16) * 64 + c * 32 + quad * 8];

    f32x4 o[4] = {};
    float lsum = 0.f;

    const int srow = tid >> 2, sc8 = (tid & 3) * 8;  // K rows
    const int vd = tid >> 2, vq = tid & 3;           // V: d row, t-quarter
    const int vp = vq >> 1, vw = (vq & 1) * 16;

#define KISSUE(k0v, b) do {                                                                 \
        ASYNC16(&Kp[kbase + (size_t)((k0v) + srow) * 64 + sc8],      &Ks[b][0][srow][sc8]); \
        ASYNC16(&Kp[kbase + (size_t)((k0v) + srow) * 64 + 32 + sc8], &Ks[b][1][srow][sc8]); \
    } while (0)
#define VLOAD(k0v) do {                                                           \
        vr0 = *(const uint4*)&Vt[(size_t)vd * 2048 + (k0v) + vq * 16];            \
        vr1 = *(const uint4*)&Vt[(size_t)vd * 2048 + (k0v) + vq * 16 + 8];        \
    } while (0)
#define VSTORE(b) do {                                                            \
        *(uint2*)&Vs[b][vp][vd][vw]      = make_uint2(vr0.x, vr0.y);              \
        *(uint2*)&Vs[b][vp][vd][vw + 4]  = make_uint2(vr0.z, vr0.w);              \
        *(uint2*)&Vs[b][vp][vd][vw + 8]  = make_uint2(vr1.x, vr1.y);              \
        *(uint2*)&Vs[b][vp][vd][vw + 12] = make_uint2(vr1.z, vr1.w);              \
    } while (0)

    uint4 vr0, vr1;
    VLOAD(0); KISSUE(0, 0); VSTORE(0);
    for (int g = 0; g < nk; g++) {
        __syncthreads();
        const int cur = g & 1, nxt = cur ^ 1;
        const bool more = (g + 1 < nk);
        if (more) { VLOAD((g + 1) * 64); KISSUE((g + 1) * 64, nxt); }
        const int k0 = g * 64;
        const bool diag = (g == nk - 1);

        f32x4 st[4];
        for (int kt = 0; kt < 4; kt++) {
            f32x4 a = {0.f, 0.f, 0.f, 0.f};
            a = __builtin_amdgcn_mfma_f32_16x16x32_bf16(
                    *(const bf16x8*)&Ks[cur][0][kt * 16 + l16][quad * 8], qf[0], a, 0, 0, 0);
            a = __builtin_amdgcn_mfma_f32_16x16x32_bf16(
                    *(const bf16x8*)&Ks[cur][1][kt * 16 + l16][quad * 8], qf[1], a, 0, 0, 0);
            st[kt] = a;
        }
        for (int kt = 0; kt < 4; kt++) {
            h4 pa;
            if (diag) {
                for (int r = 0; r < 4; r++) {
                    int tg = k0 + kt * 16 + quad * 4 + r;
                    float p = (tg <= qg) ? __builtin_amdgcn_exp2f(st[kt][r]) : 0.f;
                    lsum += p; pa[r] = (_Float16)p;
                }
            } else {
                for (int r = 0; r < 4; r++) {
                    float p = __builtin_amdgcn_exp2f(st[kt][r]);
                    lsum += p; pa[r] = (_Float16)p;
                }
            }
            const int tp = kt >> 1, tw = (kt & 1) * 16 + quad * 4;
            for (int dc = 0; dc < 4; dc++) {
                h4 vb = *(const h4*)&Vs[cur][tp][dc * 16 + l16][tw];
                o[dc] = __builtin_amdgcn_mfma_f32_16x16x16f16(pa, vb, o[dc], 0, 0, 0);
            }
        }
        if (more) VSTORE(nxt);
    }
#undef KISSUE
#undef VLOAD
#undef VSTORE

    lsum += __shfl_xor(lsum, 16, 64);
    lsum += __shfl_xor(lsum, 32, 64);
    float rinv = 1.f / lsum;
    float rq[4];
    for (int r = 0; r < 4; r++)
        rq[r] = __shfl(rinv, quad * 4 + r, 64);

    const int b = bh >> 4, h = bh & 15;
    for (int dc = 0; dc < 4; dc++)
        for (int r = 0; r < 4; r++) {
            int q = qrow + quad * 4 + r;
            Hb[((size_t)(b * 2048 + q)) * 1024 + h * 64 + dc * 16 + l16] = f2bf(o[dc][r] * rq[r]);
        }
}

// ---------------- layernorm (row = block), optional bf16 copy ----------------
__global__ __launch_bounds__(256) void ln_kernel(
    float* __restrict__ y, const float* __restrict__ g, const float* __restrict__ be,
    u16* __restrict__ bf_out)
{
    __shared__ float red[8];
    const int row = blockIdx.x, tid = threadIdx.x;
    float4 v = *(const float4*)&y[(size_t)row * 1024 + tid * 4];
    float sum = v.x + v.y + v.z + v.w;
    float sq  = v.x * v.x + v.y * v.y + v.z * v.z + v.w * v.w;
    for (int off = 1; off < 64; off <<= 1) {
        sum += __shfl_xor(sum, off, 64);
        sq  += __shfl_xor(sq,  off, 64);
    }
    int wave = tid >> 6;
    if ((tid & 63) == 0) { red[wave * 2] = sum; red[wave * 2 + 1] = sq; }
    __syncthreads();
    sum = red[0] + red[2] + red[4] + red[6];
    sq  = red[1] + red[3] + red[5] + red[7];
    float mu = sum * (1.f / 1024.f);
    float var = sq * (1.f / 1024.f) - mu * mu;
    float rstd = rsqrtf(var + 1e-5f);
    float4 gv = *(const float4*)&g[tid * 4];
    float4 bv = *(const float4*)&be[tid * 4];
    float4 ov;
    ov.x = (v.x - mu) * rstd * gv.x + bv.x;
    ov.y = (v.y - mu) * rstd * gv.y + bv.y;
    ov.z = (v.z - mu) * rstd * gv.z + bv.z;
    ov.w = (v.w - mu) * rstd * gv.w + bv.w;
    *(float4*)&y[(size_t)row * 1024 + tid * 4] = ov;
    if (bf_out) {
        ushort4 ob;
        ob.x = f2bf(ov.x); ob.y = f2bf(ov.y); ob.z = f2bf(ov.z); ob.w = f2bf(ov.w);
        *(ushort4*)&bf_out[(size_t)row * 1024 + tid * 4] = ob;
    }
}

// ---------------- launch ----------------
extern "C" void kernel_launch(void* const* d_in, const int* in_sizes, int n_in,
                              void* d_out, int out_size, void* d_ws, size_t ws_size,
                              hipStream_t stream)
{
    const float* x     = (const float*)d_in[0];
    const float* Wqkv  = (const float*)d_in[1];
    const float* bqkv  = (const float*)d_in[2];
    const float* Wout  = (const float*)d_in[3];
    const float* bout  = (const float*)d_in[4];
    const float* g1    = (const float*)d_in[5];
    const float* be1   = (const float*)d_in[6];
    const float* Wff1  = (const float*)d_in[7];
    const float* bff1  = (const float*)d_in[8];
    const float* Wff2  = (const float*)d_in[9];
    const float* bff2  = (const float*)d_in[10];
    const float* g2    = (const float*)d_in[11];
    const float* be2   = (const float*)d_in[12];
    float* out = (float*)d_out;

    char* wsb = (char*)d_ws;
    u16* WqkvT = (u16*)(wsb + 0);                   //  6 MB [3072,1024]
    u16* WoutT = (u16*)(wsb + 6291456);             //  2 MB [1024,1024]
    u16* Wff1T = (u16*)(wsb + 8388608);             //  4 MB [2048,1024]
    u16* Wff2T = (u16*)(wsb + 12582912);            //  4 MB [1024,2048]
    u16* xb    = (u16*)(wsb + 16777216);            //  8 MB [4096,1024]; reused as VT
    u16* Qp    = (u16*)(wsb + 25165824);            //  8 MB [B,H,T,D] bf16
    u16* Kp    = (u16*)(wsb + 33554432);            //  8 MB bf16
    u16* Vp    = (u16*)(wsb + 41943040);            //  8 MB f16
    u16* Hb    = (u16*)(wsb + 50331648);            //  8 MB [4096,1024] bf16
    u16* x1b   = (u16*)(wsb + 58720256);            //  8 MB [4096,1024] bf16
    u16* ff1b  = (u16*)(wsb + 67108864);            // 16 MB [4096,2048] bf16
    float* y1  = (float*)(wsb + 83886080);          // 16 MB fp32 [4096,1024]
    u16* VTg   = xb;                                // V^T f16 [bh][d][t]

    // fused weight prep (4 transposes + x convert in 1 launch)
    hipLaunchKernelGGL(prep_weights, dim3(9216), dim3(32, 8), 0, stream,
                       Wqkv, WqkvT, Wout, WoutT, Wff1, Wff1T, Wff2, Wff2T, x, xb);

    // QKV projection (128x128, 768 blocks, XCD-swizzled)
    hipLaunchKernelGGL(gemm_qkv_kernel, dim3(768), dim3(256), 0, stream,
                       xb, WqkvT, bqkv, Qp, Kp, Vp);
    // V transpose (f16 passthrough; overwrites xb — dead now)
    hipLaunchKernelGGL(vtrans_kernel, dim3(32, 32), dim3(64, 8), 0, stream, Vp, VTg);
    // attention (v10)
    hipLaunchKernelGGL(attn_kernel, dim3(1024), dim3(256), 0, stream, Qp, Kp, VTg, Hb);
    // out projection + residual (x fp32) -> y1 fp32   (64x64 BK=64, 1024 blocks)
    hipLaunchKernelGGL((gemm64x64_kernel<0>), dim3(16, 64), dim3(256), 0, stream,
                       Hb, WoutT, bout, y1, (const void*)x, 4096, 1024, 1024);
    // LN1 in-place on y1, emit bf16 x1b
    hipLaunchKernelGGL(ln_kernel, dim3(4096), dim3(256), 0, stream, y1, g1, be1, x1b);
    // FF1 + relu -> ff1b bf16   (64x128, 1024 blocks)
    hipLaunchKernelGGL(gemm64_kernel, dim3(16, 64), dim3(256), 0, stream,
                       x1b, Wff1T, bff1, ff1b, 4096, 2048, 1024);
    // FF2 + residual (x1b bf16) -> d_out fp32   (64x64 BK=64, 1024 blocks)
    hipLaunchKernelGGL((gemm64x64_kernel<1>), dim3(16, 64), dim3(256), 0, stream,
                       ff1b, Wff2T, bff2, out, (const void*)x1b, 4096, 1024, 2048);
    // LN2 in-place on d_out
    hipLaunchKernelGGL(ln_kernel, dim3(4096), dim3(256), 0, stream, out, g2, be2, (u16*)nullptr);
}